// Round 1
// baseline (160.173 us; speedup 1.0000x reference)
//
#include <hip/hip_runtime.h>
#include <cstdint>
#include <cstddef>

constexpr int BB = 64;
constexpr int NN = 1024;
constexpr int DD = 256;
constexpr int PP = 256;

typedef short short8 __attribute__((ext_vector_type(8)));
typedef float f32x4 __attribute__((ext_vector_type(4)));

__device__ __forceinline__ unsigned short f2bf(float f) {
    union { float f; uint32_t u; } v; v.f = f;
    uint32_t u = v.u;
    uint32_t r = (u + 0x7FFFu + ((u >> 16) & 1u)) >> 16;
    return (unsigned short)r;
}

// ---- prep: wt[j][d] = bf16(w[d][j]) for j<256 -> w1, else w2 (transposed, bf16) ----
__global__ void prep_wt(const float* __restrict__ w1, const float* __restrict__ w2,
                        unsigned short* __restrict__ wt) {
    int j = blockIdx.x;        // 0..511
    int d = threadIdx.x;       // 0..255
    const float* w = (j < PP) ? w1 : w2;
    int jj = j & (PP - 1);
    wt[j * DD + d] = f2bf(w[d * PP + jj]);
}

// ---- xv[b,n] = x[b,n,:] . w4 ----
__global__ void calc_xv(const float* __restrict__ x, const float* __restrict__ w4,
                        float* __restrict__ xv) {
    int row = blockIdx.x * 4 + (threadIdx.x >> 6);   // wave per row
    int lane = threadIdx.x & 63;
    float4 v = reinterpret_cast<const float4*>(x + (size_t)row * DD)[lane];
    float4 w = reinterpret_cast<const float4*>(w4)[lane];
    float s = v.x * w.x + v.y * w.y + v.z * w.z + v.w * w.w;
    #pragma unroll
    for (int off = 1; off < 64; off <<= 1) s += __shfl_xor(s, off);
    if (lane == 0) xv[row] = s;
}

// ---- q,k = sigmoid(x @ W): block = 64 rows, loops over 8 col-tiles of 64 ----
__global__ __launch_bounds__(256) void qk_gemm(const float* __restrict__ x,
                                               const unsigned short* __restrict__ wt,
                                               unsigned short* __restrict__ qb,
                                               unsigned short* __restrict__ kb) {
    __shared__ __align__(16) unsigned short xs[64 * 256];   // x tile bf16, swizzled
    __shared__ __align__(16) unsigned short wsm[64 * 256];  // wt tile bf16, swizzled
    const int t = threadIdx.x;
    const int rowTile = blockIdx.x;            // 1024 blocks * 64 rows
    // stage x tile (f32 -> bf16), XOR-swizzled: byte ^= (row&7)<<4
    #pragma unroll
    for (int i = 0; i < 16; i++) {
        int idx = t + i * 256;
        int row = idx >> 6;
        int c4 = idx & 63;
        float4 v = reinterpret_cast<const float4*>(x + ((size_t)rowTile * 64 + row) * DD)[c4];
        uint64_t pk = (uint64_t)f2bf(v.x) | ((uint64_t)f2bf(v.y) << 16)
                    | ((uint64_t)f2bf(v.z) << 32) | ((uint64_t)f2bf(v.w) << 48);
        uint32_t byte = (uint32_t)(row * 512 + c4 * 8) ^ (uint32_t)((row & 7) << 4);
        *reinterpret_cast<uint64_t*>(reinterpret_cast<char*>(xs) + byte) = pk;
    }
    __syncthreads();
    const int wv = t >> 6, lane = t & 63, l15 = lane & 15, l4 = lane >> 4;
    // A fragments hoisted: lane holds A[row=l15][k = kc*32 + l4*8 + e]
    short8 af[8];
    #pragma unroll
    for (int kc = 0; kc < 8; kc++) {
        int row = wv * 16 + l15;
        uint32_t byte = (uint32_t)(row * 512 + kc * 64 + l4 * 16) ^ (uint32_t)((row & 7) << 4);
        af[kc] = *reinterpret_cast<const short8*>(reinterpret_cast<const char*>(xs) + byte);
    }
    for (int ct = 0; ct < 8; ct++) {
        __syncthreads();
        // stage wt tile rows ct*64 .. +63  (already bf16)
        #pragma unroll
        for (int i = 0; i < 8; i++) {
            int idx = t + i * 256;
            int row = idx >> 5;
            int c16 = idx & 31;
            short8 v = *reinterpret_cast<const short8*>(wt + ((size_t)(ct * 64 + row)) * DD + c16 * 8);
            uint32_t byte = (uint32_t)(row * 512 + c16 * 16) ^ (uint32_t)((row & 7) << 4);
            *reinterpret_cast<short8*>(reinterpret_cast<char*>(wsm) + byte) = v;
        }
        __syncthreads();
        unsigned short* outp = (ct < 4) ? qb : kb;
        int pc0 = (ct & 3) * 64;
        #pragma unroll
        for (int st = 0; st < 4; st++) {
            f32x4 a = {0.f, 0.f, 0.f, 0.f};
            #pragma unroll
            for (int kc = 0; kc < 8; kc++) {
                int row = st * 16 + l15;     // B frag: lane holds B[k][j=l15] = wt[col j][k]
                uint32_t byte = (uint32_t)(row * 512 + kc * 64 + l4 * 16) ^ (uint32_t)((row & 7) << 4);
                short8 bfr = *reinterpret_cast<const short8*>(reinterpret_cast<const char*>(wsm) + byte);
                a = __builtin_amdgcn_mfma_f32_16x16x32_bf16(af[kc], bfr, a, 0, 0, 0);
            }
            #pragma unroll
            for (int r = 0; r < 4; r++) {
                int grow = rowTile * 64 + wv * 16 + l4 * 4 + r;   // D row = (lane>>4)*4+r
                int gcol = pc0 + st * 16 + l15;                   // D col = lane&15
                float sg = 1.f / (1.f + __expf(-a[r]));
                outp[(size_t)grow * PP + gcol] = f2bf(sg);
            }
        }
    }
}

// ---- logit[b,n] = sum_m softmax_m(q.k/16) * xv[b,m]  (flash-style, scalar V) ----
__global__ __launch_bounds__(256) void attn_logit(const unsigned short* __restrict__ qb,
                                                  const unsigned short* __restrict__ kb,
                                                  const float* __restrict__ xv,
                                                  float* __restrict__ logit) {
    __shared__ __align__(16) unsigned short ks[64 * 256];
    __shared__ float xvs[1024];
    const int b = blockIdx.x;
    const int nt = blockIdx.y;                 // 16 tiles of 64 q-rows
    const int t = threadIdx.x, wv = t >> 6, lane = t & 63, l15 = lane & 15, l4 = lane >> 4;
    #pragma unroll
    for (int i = 0; i < 4; i++) xvs[t + i * 256] = xv[b * NN + t + i * 256];
    // hoist Q fragments (reused over all 16 m-tiles)
    short8 qf[8];
    const unsigned short* qrow = qb + ((size_t)(b * NN + nt * 64 + wv * 16 + l15)) * PP;
    #pragma unroll
    for (int kc = 0; kc < 8; kc++)
        qf[kc] = *reinterpret_cast<const short8*>(qrow + kc * 32 + l4 * 8);
    float denom[4] = {0.f, 0.f, 0.f, 0.f}, numer[4] = {0.f, 0.f, 0.f, 0.f};
    for (int mt = 0; mt < 16; mt++) {
        __syncthreads();
        #pragma unroll
        for (int i = 0; i < 8; i++) {
            int idx = t + i * 256;
            int row = idx >> 5;
            int c16 = idx & 31;
            short8 v = *reinterpret_cast<const short8*>(kb + ((size_t)(b * NN + mt * 64 + row)) * PP + c16 * 8);
            uint32_t byte = (uint32_t)(row * 512 + c16 * 16) ^ (uint32_t)((row & 7) << 4);
            *reinterpret_cast<short8*>(reinterpret_cast<char*>(ks) + byte) = v;
        }
        __syncthreads();
        #pragma unroll
        for (int st = 0; st < 4; st++) {
            f32x4 a = {0.f, 0.f, 0.f, 0.f};
            #pragma unroll
            for (int kc = 0; kc < 8; kc++) {
                int row = st * 16 + l15;
                uint32_t byte = (uint32_t)(row * 512 + kc * 64 + l4 * 16) ^ (uint32_t)((row & 7) << 4);
                short8 bfr = *reinterpret_cast<const short8*>(reinterpret_cast<const char*>(ks) + byte);
                a = __builtin_amdgcn_mfma_f32_16x16x32_bf16(qf[kc], bfr, a, 0, 0, 0);
            }
            float xvv = xvs[mt * 64 + st * 16 + l15];
            #pragma unroll
            for (int r = 0; r < 4; r++) {
                float e = __expf(a[r] * 0.0625f);   // s in (0,16): no max-subtract needed
                denom[r] += e;
                numer[r] += e * xvv;
            }
        }
    }
    // reduce over the 16 lanes that share each D-row (cols of S)
    #pragma unroll
    for (int off = 1; off < 16; off <<= 1) {
        #pragma unroll
        for (int r = 0; r < 4; r++) {
            denom[r] += __shfl_xor(denom[r], off);
            numer[r] += __shfl_xor(numer[r], off);
        }
    }
    if (l15 == 0) {
        #pragma unroll
        for (int r = 0; r < 4; r++) {
            int n = nt * 64 + wv * 16 + l4 * 4 + r;
            logit[b * NN + n] = numer[r] / denom[r];
        }
    }
}

// ---- sentence partials: a = softmax_n(logit[b,:]); part[b,ch,:] = sum_{n in chunk} a_n x[b,n,:] ----
__global__ __launch_bounds__(256) void sent_partial(const float* __restrict__ x,
                                                    const float* __restrict__ logit,
                                                    float* __restrict__ part) {
    __shared__ float al[1024];
    __shared__ float redA[4];
    __shared__ float redB[4];
    const int b = blockIdx.x, ch = blockIdx.y;
    const int t = threadIdx.x;
    float l[4];
    #pragma unroll
    for (int i = 0; i < 4; i++) l[i] = logit[b * NN + t + i * 256];
    float mx = fmaxf(fmaxf(l[0], l[1]), fmaxf(l[2], l[3]));
    #pragma unroll
    for (int off = 1; off < 64; off <<= 1) mx = fmaxf(mx, __shfl_xor(mx, off));
    if ((t & 63) == 0) redA[t >> 6] = mx;
    __syncthreads();
    mx = fmaxf(fmaxf(redA[0], redA[1]), fmaxf(redA[2], redA[3]));
    float e[4], es = 0.f;
    #pragma unroll
    for (int i = 0; i < 4; i++) { e[i] = __expf(l[i] - mx); es += e[i]; }
    #pragma unroll
    for (int off = 1; off < 64; off <<= 1) es += __shfl_xor(es, off);
    if ((t & 63) == 0) redB[t >> 6] = es;
    __syncthreads();
    float inv = 1.f / (redB[0] + redB[1] + redB[2] + redB[3]);
    #pragma unroll
    for (int i = 0; i < 4; i++) al[t + i * 256] = e[i] * inv;
    __syncthreads();
    float acc = 0.f;
    const float* xb = x + (size_t)b * NN * DD + (size_t)ch * 256 * DD + t;
    #pragma unroll 4
    for (int n = 0; n < 256; n++)
        acc += al[ch * 256 + n] * xb[(size_t)n * DD];   // coalesced: thread t reads col t
    part[(b * 4 + ch) * DD + t] = acc;
}

__global__ void sent_final(const float* __restrict__ part, float* __restrict__ out) {
    int b = blockIdx.x, t = threadIdx.x;
    float s = 0.f;
    #pragma unroll
    for (int c = 0; c < 4; c++) s += part[(b * 4 + c) * DD + t];
    out[b * DD + t] = s;
}

extern "C" void kernel_launch(void* const* d_in, const int* in_sizes, int n_in,
                              void* d_out, int out_size, void* d_ws, size_t ws_size,
                              hipStream_t stream) {
    (void)in_sizes; (void)n_in; (void)out_size; (void)ws_size;
    const float* x  = (const float*)d_in[0];
    const float* w1 = (const float*)d_in[1];
    const float* w2 = (const float*)d_in[2];
    const float* w4 = (const float*)d_in[3];
    float* out = (float*)d_out;

    char* ws = (char*)d_ws;
    const size_t MB = 1024 * 1024;
    unsigned short* qb   = (unsigned short*)(ws);                    // 32 MB
    unsigned short* kb   = (unsigned short*)(ws + 32 * MB);          // 32 MB
    unsigned short* wt   = (unsigned short*)(ws + 64 * MB);          // 256 KB
    float*          xv   = (float*)(ws + 64 * MB + 256 * 1024);     // 256 KB
    float*          lgt  = (float*)(ws + 64 * MB + 512 * 1024);     // 256 KB
    float*          part = (float*)(ws + 64 * MB + 768 * 1024);     // 256 KB

    prep_wt<<<dim3(2 * PP), dim3(DD), 0, stream>>>(w1, w2, wt);
    calc_xv<<<dim3(BB * NN / 4), dim3(256), 0, stream>>>(x, w4, xv);
    qk_gemm<<<dim3(BB * NN / 64), dim3(256), 0, stream>>>(x, wt, qb, kb);
    attn_logit<<<dim3(BB, NN / 64), dim3(256), 0, stream>>>(qb, kb, xv, lgt);
    sent_partial<<<dim3(BB, 4), dim3(256), 0, stream>>>(x, lgt, part);
    sent_final<<<dim3(BB), dim3(DD), 0, stream>>>(part, out);
}

// Round 2
// 132.612 us; speedup vs baseline: 1.2078x; 1.2078x over previous
//
#include <hip/hip_runtime.h>
#include <cstdint>
#include <cstddef>

constexpr int BB = 64;
constexpr int NN = 1024;
constexpr int DD = 256;
constexpr int PP = 256;

typedef short short8 __attribute__((ext_vector_type(8)));
typedef float f32x4 __attribute__((ext_vector_type(4)));

__device__ __forceinline__ unsigned short f2bf(float f) {
    union { float f; uint32_t u; } v; v.f = f;
    uint32_t u = v.u;
    uint32_t r = (u + 0x7FFFu + ((u >> 16) & 1u)) >> 16;
    return (unsigned short)r;
}

// async global->LDS, 16B per lane, LDS dest = wave-uniform base + lane*16
__device__ __forceinline__ void async_load16(void* lds, const void* g) {
    __builtin_amdgcn_global_load_lds(
        (const __attribute__((address_space(1))) unsigned int*)g,
        (__attribute__((address_space(3))) unsigned int*)lds, 16, 0, 0);
}

// Stage a 64-row x 256-col bf16 tile (32KB) into LDS, XOR-swizzled via
// pre-swizzled SOURCE (LDS write stays linear). src_base = row 0 of tile.
__device__ __forceinline__ void stage_tile(const unsigned short* src_base,
                                           unsigned short* lds, int wv, int lane) {
    const char* base = (const char*)src_base;
    char* dst0 = (char*)lds + wv * 8192;
    #pragma unroll
    for (int i = 0; i < 8; i++) {
        int row = wv * 16 + i * 2 + (lane >> 5);
        int blk = (lane & 31) ^ (row & 7);
        async_load16(dst0 + i * 1024, base + row * 512 + blk * 16);
    }
}

// Read a 16B MFMA fragment from the swizzled tile. kidx = kc*4 + l4.
__device__ __forceinline__ short8 lds_frag(const unsigned short* lds, int row, int kidx) {
    uint32_t byte = (uint32_t)(row * 512) + (uint32_t)(((kidx ^ (row & 7)) & 31) << 4);
    return *reinterpret_cast<const short8*>(reinterpret_cast<const char*>(lds) + byte);
}

// ---- prep: wt[j][d] = bf16(w[d][j]) for j<256 -> w1, else w2 (transposed, bf16) ----
__global__ void prep_wt(const float* __restrict__ w1, const float* __restrict__ w2,
                        unsigned short* __restrict__ wt) {
    int j = blockIdx.x;        // 0..511
    int d = threadIdx.x;       // 0..255
    const float* w = (j < PP) ? w1 : w2;
    int jj = j & (PP - 1);
    wt[j * DD + d] = f2bf(w[d * PP + jj]);
}

// ---- q,k = sigmoid(x @ W)  +  xv = x @ w4, fused ----
// Block: 256 threads = 4 waves; each wave owns 64 x-rows (4 sets of 16).
// x-fragments hoisted in registers; wt tiles streamed via global_load_lds dbuf.
// MFMA operands swapped (A = wt, B = x) so each lane's 4 acc values are 4
// consecutive p-columns -> 8B vector stores.
__global__ __launch_bounds__(256) void qk_fused(const float* __restrict__ x,
                                                const unsigned short* __restrict__ wt,
                                                const float* __restrict__ w4,
                                                unsigned short* __restrict__ qb,
                                                unsigned short* __restrict__ kb,
                                                float* __restrict__ xv) {
    __shared__ __align__(16) unsigned short wtile[2][16384];   // 2 x 32KB
    const int t = threadIdx.x, wv = t >> 6, lane = t & 63, l15 = lane & 15, l4 = lane >> 4;
    const int rowBase = blockIdx.x * 256;

    stage_tile(wt, wtile[0], wv, lane);   // ct=0 tile

    // hoist x fragments (bf16) + accumulate xv partials (f32)
    short8 xf[4][8];
    float xvp[4] = {0.f, 0.f, 0.f, 0.f};
    #pragma unroll
    for (int kc = 0; kc < 8; kc++) {
        float4 w4a = *reinterpret_cast<const float4*>(w4 + kc * 32 + l4 * 8);
        float4 w4b = *reinterpret_cast<const float4*>(w4 + kc * 32 + l4 * 8 + 4);
        #pragma unroll
        for (int s = 0; s < 4; s++) {
            const float* xr = x + (size_t)(rowBase + wv * 64 + s * 16 + l15) * DD + kc * 32 + l4 * 8;
            float4 a = *reinterpret_cast<const float4*>(xr);
            float4 b = *reinterpret_cast<const float4*>(xr + 4);
            xvp[s] += a.x * w4a.x + a.y * w4a.y + a.z * w4a.z + a.w * w4a.w
                    + b.x * w4b.x + b.y * w4b.y + b.z * w4b.z + b.w * w4b.w;
            short8 f;
            f[0] = (short)f2bf(a.x); f[1] = (short)f2bf(a.y);
            f[2] = (short)f2bf(a.z); f[3] = (short)f2bf(a.w);
            f[4] = (short)f2bf(b.x); f[5] = (short)f2bf(b.y);
            f[6] = (short)f2bf(b.z); f[7] = (short)f2bf(b.w);
            xf[s][kc] = f;
        }
    }
    // xv: reduce over the 4 lanes (l4 = 0..3) sharing each row
    #pragma unroll
    for (int s = 0; s < 4; s++) {
        xvp[s] += __shfl_xor(xvp[s], 16);
        xvp[s] += __shfl_xor(xvp[s], 32);
        if (l4 == 0) xv[rowBase + wv * 64 + s * 16 + l15] = xvp[s];
    }

    __syncthreads();   // drains stage of ct=0
    int buf = 0;
    for (int ct = 0; ct < 8; ct++) {
        if (ct + 1 < 8) stage_tile(wt + (size_t)(ct + 1) * 64 * DD, wtile[buf ^ 1], wv, lane);
        unsigned short* outp = (ct < 4) ? qb : kb;
        const int pc0 = (ct & 3) * 64;
        #pragma unroll
        for (int st = 0; st < 4; st++) {
            f32x4 z = {0.f, 0.f, 0.f, 0.f};
            f32x4 acc[4] = {z, z, z, z};
            #pragma unroll
            for (int kc = 0; kc < 8; kc++) {
                short8 wf = lds_frag(wtile[buf], st * 16 + l15, kc * 4 + l4);
                #pragma unroll
                for (int s = 0; s < 4; s++)
                    acc[s] = __builtin_amdgcn_mfma_f32_16x16x32_bf16(wf, xf[s][kc], acc[s], 0, 0, 0);
            }
            // D: col(l15) = x-row, row(l4*4+r) = p-col -> 4 consecutive p per lane
            #pragma unroll
            for (int s = 0; s < 4; s++) {
                ushort4 pk;
                pk.x = f2bf(1.f / (1.f + __expf(-acc[s][0])));
                pk.y = f2bf(1.f / (1.f + __expf(-acc[s][1])));
                pk.z = f2bf(1.f / (1.f + __expf(-acc[s][2])));
                pk.w = f2bf(1.f / (1.f + __expf(-acc[s][3])));
                size_t off = (size_t)(rowBase + wv * 64 + s * 16 + l15) * PP + pc0 + st * 16 + l4 * 4;
                *reinterpret_cast<ushort4*>(outp + off) = pk;
            }
        }
        __syncthreads();
        buf ^= 1;
    }
}

// ---- logit[b,n] = sum_m softmax_m(q.k/16) * xv[b,m]  (flash-style, scalar V) ----
// Block: 256 threads = 4 waves, 256 q-rows (wave = 64 q, 4 sets). Q hoisted in
// registers; K tiles (64 m-rows) streamed via global_load_lds dbuf.
__global__ __launch_bounds__(256) void attn_logit(const unsigned short* __restrict__ qb,
                                                  const unsigned short* __restrict__ kb,
                                                  const float* __restrict__ xv,
                                                  float* __restrict__ logit) {
    __shared__ __align__(16) unsigned short kt[2][16384];   // 2 x 32KB
    __shared__ float xvs[1024];
    const int b = blockIdx.x;
    const int qt = blockIdx.y;    // 4 tiles of 256 q-rows
    const int t = threadIdx.x, wv = t >> 6, lane = t & 63, l15 = lane & 15, l4 = lane >> 4;
    const unsigned short* kbb = kb + (size_t)b * NN * PP;

    stage_tile(kbb, kt[0], wv, lane);   // mt=0

    #pragma unroll
    for (int i = 0; i < 4; i++) xvs[t + i * 256] = xv[b * NN + t + i * 256];

    // hoist Q fragments: 4 sets x 8 kc
    short8 qf[4][8];
    #pragma unroll
    for (int s = 0; s < 4; s++) {
        const unsigned short* qrow = qb + ((size_t)(b * NN + qt * 256 + wv * 64 + s * 16 + l15)) * PP;
        #pragma unroll
        for (int kc = 0; kc < 8; kc++)
            qf[s][kc] = *reinterpret_cast<const short8*>(qrow + kc * 32 + l4 * 8);
    }

    float den[4][4], num[4][4];
    #pragma unroll
    for (int s = 0; s < 4; s++)
        #pragma unroll
        for (int r = 0; r < 4; r++) { den[s][r] = 0.f; num[s][r] = 0.f; }

    __syncthreads();   // drains stage of mt=0 + xvs
    int buf = 0;
    for (int mt = 0; mt < 16; mt++) {
        if (mt + 1 < 16) stage_tile(kbb + (size_t)(mt + 1) * 64 * PP, kt[buf ^ 1], wv, lane);
        #pragma unroll
        for (int st = 0; st < 4; st++) {
            f32x4 z = {0.f, 0.f, 0.f, 0.f};
            f32x4 a[4] = {z, z, z, z};
            #pragma unroll
            for (int kc = 0; kc < 8; kc++) {
                short8 kf = lds_frag(kt[buf], st * 16 + l15, kc * 4 + l4);
                #pragma unroll
                for (int s = 0; s < 4; s++)
                    a[s] = __builtin_amdgcn_mfma_f32_16x16x32_bf16(qf[s][kc], kf, a[s], 0, 0, 0);
            }
            float xvv = xvs[mt * 64 + st * 16 + l15];
            #pragma unroll
            for (int s = 0; s < 4; s++)
                #pragma unroll
                for (int r = 0; r < 4; r++) {
                    float e = __expf(a[s][r] * 0.0625f);   // s in (0,16): no max-subtract needed
                    den[s][r] += e;
                    num[s][r] += e * xvv;
                }
        }
        __syncthreads();
        buf ^= 1;
    }
    // reduce over the 16 lanes (l15 group) holding different m-columns
    #pragma unroll
    for (int s = 0; s < 4; s++)
        #pragma unroll
        for (int r = 0; r < 4; r++) {
            #pragma unroll
            for (int off = 1; off < 16; off <<= 1) {
                den[s][r] += __shfl_xor(den[s][r], off);
                num[s][r] += __shfl_xor(num[s][r], off);
            }
        }
    if (l15 == 0) {
        #pragma unroll
        for (int s = 0; s < 4; s++)
            #pragma unroll
            for (int r = 0; r < 4; r++) {
                int n = qt * 256 + wv * 64 + s * 16 + l4 * 4 + r;
                logit[b * NN + n] = num[s][r] / den[s][r];
            }
    }
}

// ---- sentence partials: a = softmax_n(logit[b,:]); part[b,ch,:] = sum_{n in chunk} a_n x[b,n,:] ----
__global__ __launch_bounds__(256) void sent_partial(const float* __restrict__ x,
                                                    const float* __restrict__ logit,
                                                    float* __restrict__ part) {
    __shared__ float al[1024];
    __shared__ float redA[4];
    __shared__ float redB[4];
    const int b = blockIdx.x, ch = blockIdx.y;
    const int t = threadIdx.x;
    float l[4];
    #pragma unroll
    for (int i = 0; i < 4; i++) l[i] = logit[b * NN + t + i * 256];
    float mx = fmaxf(fmaxf(l[0], l[1]), fmaxf(l[2], l[3]));
    #pragma unroll
    for (int off = 1; off < 64; off <<= 1) mx = fmaxf(mx, __shfl_xor(mx, off));
    if ((t & 63) == 0) redA[t >> 6] = mx;
    __syncthreads();
    mx = fmaxf(fmaxf(redA[0], redA[1]), fmaxf(redA[2], redA[3]));
    float e[4], es = 0.f;
    #pragma unroll
    for (int i = 0; i < 4; i++) { e[i] = __expf(l[i] - mx); es += e[i]; }
    #pragma unroll
    for (int off = 1; off < 64; off <<= 1) es += __shfl_xor(es, off);
    if ((t & 63) == 0) redB[t >> 6] = es;
    __syncthreads();
    float inv = 1.f / (redB[0] + redB[1] + redB[2] + redB[3]);
    #pragma unroll
    for (int i = 0; i < 4; i++) al[t + i * 256] = e[i] * inv;
    __syncthreads();
    float acc = 0.f;
    const float* xb = x + (size_t)b * NN * DD + (size_t)ch * 256 * DD + t;
    #pragma unroll 4
    for (int n = 0; n < 256; n++)
        acc += al[ch * 256 + n] * xb[(size_t)n * DD];   // coalesced: thread t reads col t
    part[(b * 4 + ch) * DD + t] = acc;
}

__global__ void sent_final(const float* __restrict__ part, float* __restrict__ out) {
    int b = blockIdx.x, t = threadIdx.x;
    float s = 0.f;
    #pragma unroll
    for (int c = 0; c < 4; c++) s += part[(b * 4 + c) * DD + t];
    out[b * DD + t] = s;
}

extern "C" void kernel_launch(void* const* d_in, const int* in_sizes, int n_in,
                              void* d_out, int out_size, void* d_ws, size_t ws_size,
                              hipStream_t stream) {
    (void)in_sizes; (void)n_in; (void)out_size; (void)ws_size;
    const float* x  = (const float*)d_in[0];
    const float* w1 = (const float*)d_in[1];
    const float* w2 = (const float*)d_in[2];
    const float* w4 = (const float*)d_in[3];
    float* out = (float*)d_out;

    char* ws = (char*)d_ws;
    const size_t MB = 1024 * 1024;
    unsigned short* qb   = (unsigned short*)(ws);                    // 32 MB
    unsigned short* kb   = (unsigned short*)(ws + 32 * MB);          // 32 MB
    unsigned short* wt   = (unsigned short*)(ws + 64 * MB);          // 256 KB
    float*          xv   = (float*)(ws + 64 * MB + 256 * 1024);     // 256 KB
    float*          lgt  = (float*)(ws + 64 * MB + 512 * 1024);     // 256 KB
    float*          part = (float*)(ws + 64 * MB + 768 * 1024);     // 256 KB

    prep_wt<<<dim3(2 * PP), dim3(DD), 0, stream>>>(w1, w2, wt);
    qk_fused<<<dim3(BB * NN / 256), dim3(256), 0, stream>>>(x, wt, w4, qb, kb, xv);
    attn_logit<<<dim3(BB, 4), dim3(256), 0, stream>>>(qb, kb, xv, lgt);
    sent_partial<<<dim3(BB, 4), dim3(256), 0, stream>>>(x, lgt, part);
    sent_final<<<dim3(BB), dim3(DD), 0, stream>>>(part, out);
}